// Round 3
// baseline (115.654 us; speedup 1.0000x reference)
//
#include <hip/hip_runtime.h>
#include <math.h>

#define Z     4
#define N1    192
#define NN    384          // n1 + n2
#define C     16
#define NB    10
#define H     12
#define ATILE 4
#define NAT   (NN / ATILE) // 96
#define SPLIT 6            // b-splits: 6 * 64 lanes = 384 b's

// ---------------------------------------------------------------------------
__device__ __forceinline__ float3 load_xyz(const float* __restrict__ xyz1,
                                           const float* __restrict__ xyz2,
                                           int z, int node) {
    const float* p = (node < N1) ? (xyz1 + (z * N1 + node) * 3)
                                 : (xyz2 + (z * N1 + (node - N1)) * 3);
    return make_float3(p[0], p[1], p[2]);
}

// ---------------------------------------------------------------------------
// Kernel 1: T[z,b,h,i] = (Y0/sqrt(H)) * sum_j W_rad_out[h, i*16+j] * x[z,b,j]
// grid = Z*NN blocks, 192 threads (one per (h,i)).
// ---------------------------------------------------------------------------
__global__ void k1_precompute_T(const float* __restrict__ in1,
                                const float* __restrict__ in2,
                                const float* __restrict__ Wro,
                                float* __restrict__ T) {
    const int bid = blockIdx.x;          // z*NN + b
    const int z = bid / NN, b = bid % NN;
    const int t = threadIdx.x;           // 0..191  -> h = t>>4, i = t&15

    __shared__ float xl[C];
    if (t < C) {
        const float* xp = (b < N1) ? (in1 + (z * N1 + b) * C)
                                   : (in2 + (z * N1 + (b - N1)) * C);
        xl[t] = xp[t];
    }
    __syncthreads();

    const int h = t >> 4, i = t & 15;
    const float* w = Wro + h * (C * C) + i * C;
    float acc = 0.0f;
    #pragma unroll
    for (int j = 0; j < C; ++j) acc += w[j] * xl[j];

    // Y0 = 1/(2*sqrt(pi)) ; 1/sqrt(12)
    const float scale = 0.28209479177387814f * 0.2886751345948129f;
    T[bid * (H * C) + t] = acc * scale;
}

// ---------------------------------------------------------------------------
// Kernel 2: block = (z, tile of 4 a's, 1-of-6 b-split). 128 threads = 2 waves.
// Both waves cover the SAME 64 b's (b = sp*64 + lane); wave wv owns the
// i-halfrange [wv*8, wv*8+8). hm[4][12] hoisted; each T float4 loaded once.
// ---------------------------------------------------------------------------
__global__ __launch_bounds__(128, 4) void k2_pairs(const float* __restrict__ xyz1,
                                                   const float* __restrict__ xyz2,
                                                   const float* __restrict__ Wr1,
                                                   const float* __restrict__ T,
                                                   float* __restrict__ partial) {
    const int bid = blockIdx.x;          // (z*NAT + at)*SPLIT + sp
    const int sp  = bid % SPLIT;
    const int za  = bid / SPLIT;
    const int z   = za / NAT, at = za % NAT;
    const int a0  = at * ATILE;
    const int tid = threadIdx.x;
    const int lane = tid & 63, wv = tid >> 6;
    const int b = sp * 64 + lane;        // this lane's b

    __shared__ float W1s[NB * H];        // W_rad1 * invGN / sqrt(NB)
    __shared__ float red[2][32];
    if (tid < NB * H)
        W1s[tid] = Wr1[tid] * (0.31622776601683794f * 0.7027283689263438f);
    __syncthreads();

    const float3 pb = load_xyz(xyz1, xyz2, z, b);
    const float invSigma = 1.125f;       // 1/(0.8*10/9)

    // ---- phase 1: hm[a][h] for the 4 a's of this tile -------------------
    float hm[ATILE][H];
    #pragma unroll
    for (int aa = 0; aa < ATILE; ++aa) {
        const float3 pa = load_xyz(xyz1, xyz2, z, a0 + aa);
        const float dx = pa.x - pb.x, dy = pa.y - pb.y, dz = pa.z - pb.z;
        const float d = sqrtf(dx * dx + dy * dy + dz * dz + 1e-12f);

        float acc[H];
        #pragma unroll
        for (int h = 0; h < H; ++h) acc[h] = 0.0f;
        #pragma unroll
        for (int k = 0; k < NB; ++k) {
            const float u = (d - (float)k * (10.0f / 9.0f)) * invSigma;
            const float e = __expf(-u * u);
            #pragma unroll
            for (int h = 0; h < H; ++h) acc[h] += e * W1s[k * H + h];
        }
        #pragma unroll
        for (int h = 0; h < H; ++h)
            hm[aa][h] = acc[h] / (1.0f + __expf(-acc[h]));   // silu
    }

    // ---- phase 2: v[aa*8 + io] += hm[aa][h] * T[b][h][wv*8 + io] --------
    float v[ATILE * 8];
    #pragma unroll
    for (int p = 0; p < ATILE * 8; ++p) v[p] = 0.0f;

    const float4* tp = (const float4*)(T + (z * NN + b) * (H * C)) + wv * 2;
    #pragma unroll
    for (int h = 0; h < H; ++h) {
        const float4 t0 = tp[h * 4 + 0];
        const float4 t1 = tp[h * 4 + 1];
        #pragma unroll
        for (int aa = 0; aa < ATILE; ++aa) {
            const float f = hm[aa][h];
            const int o = aa * 8;
            v[o + 0] += f * t0.x;  v[o + 1] += f * t0.y;
            v[o + 2] += f * t0.z;  v[o + 3] += f * t0.w;
            v[o + 4] += f * t1.x;  v[o + 5] += f * t1.y;
            v[o + 6] += f * t1.z;  v[o + 7] += f * t1.w;
        }
    }

    // ---- fold-reduce 32 values across 64 lanes --------------------------
    // 5 value-halving xor steps (bits 0..4) then a plain xor-32 add.
    #pragma unroll
    for (int k = 0; k < 5; ++k) {
        const int m = 16 >> k;
        const int bsel = (lane >> k) & 1;
        #pragma unroll
        for (int j = 0; j < m; ++j) {
            const float lo = v[j], hi = v[m + j];
            const float sendv = bsel ? lo : hi;
            const float recv = __shfl_xor(sendv, 1 << k, 64);
            v[j] = (bsel ? hi : lo) + recv;
        }
    }
    {
        const float recv = __shfl_xor(v[0], 32, 64);
        v[0] += recv;
    }
    const int l = lane & 31;
    const int pos = ((l & 1) << 4) | ((l & 2) << 2) | (l & 4) |
                    ((l & 8) >> 2) | ((l & 16) >> 4);      // bitrev5
    if (lane < 32) red[wv][pos] = v[0];
    __syncthreads();

    if (tid < 64) {                       // partial[bid][a_off*16 + i]
        const int a_off = tid >> 4, i = tid & 15;
        const float val = (i < 8) ? red[0][a_off * 8 + i]
                                  : red[1][a_off * 8 + (i - 8)];
        partial[bid * 64 + tid] = val;
    }
}

// ---------------------------------------------------------------------------
// Kernel 3: per z: sum splits, abs, mask, sum over a -> s[16];
// then normalize (ddof=1) + fc3 + leaky_relu + fc2 + sigmoid.
// grid = Z blocks, 256 threads.
// ---------------------------------------------------------------------------
__global__ __launch_bounds__(256) void k3_head(const float* __restrict__ partial,
                                               const int* __restrict__ mask,
                                               const float* __restrict__ Wfc3,
                                               const float* __restrict__ Wfc2,
                                               float* __restrict__ out) {
    const int z = blockIdx.x;
    const int t = threadIdx.x;           // 256 = 16 chunks x 16 i
    const int i = t & 15, ch = t >> 4;

    __shared__ float red[16][17];
    __shared__ float sv[C];

    float acc = 0.0f;
    #pragma unroll
    for (int r = 0; r < 24; ++r) {       // 16 chunks * 24 = 384 a's
        const int a  = ch * 24 + r;
        const int at = a >> 2, t2 = a & 3;
        const int base = ((z * NAT + at) * SPLIT) * 64 + t2 * 16 + i;
        float val = 0.0f;
        #pragma unroll
        for (int s = 0; s < SPLIT; ++s) val += partial[base + s * 64];
        val = fabsf(val);
        if (mask[z * NN + a] != 0) acc += val;
    }
    red[ch][i] = acc;
    __syncthreads();
    if (t < C) {
        float s = 0.0f;
        #pragma unroll
        for (int c2 = 0; c2 < 16; ++c2) s += red[c2][t];
        sv[t] = s;
    }
    __syncthreads();

    if (t == 0) {
        float v[C];
        float mean = 0.0f;
        #pragma unroll
        for (int q = 0; q < C; ++q) { v[q] = sv[q]; mean += v[q]; }
        mean *= (1.0f / C);
        float var = 0.0f;
        #pragma unroll
        for (int q = 0; q < C; ++q) { const float d = v[q] - mean; var += d * d; }
        const float sd = sqrtf(var / (float)(C - 1)) + 1e-6f;
        #pragma unroll
        for (int q = 0; q < C; ++q) v[q] = (v[q] - mean) / sd;

        float o = 0.0f;
        #pragma unroll
        for (int k = 0; k < C; ++k) {
            float h3 = 0.0f;
            #pragma unroll
            for (int q = 0; q < C; ++q) h3 += v[q] * Wfc3[q * C + k];
            h3 *= 0.25f;                               // / sqrt(16)
            h3 = (h3 > 0.0f) ? h3 : 0.01f * h3;        // leaky_relu
            o += h3 * Wfc2[k];
        }
        o *= 0.25f;
        out[z] = 1.0f / (1.0f + __expf(-o));
    }
}

// ---------------------------------------------------------------------------
extern "C" void kernel_launch(void* const* d_in, const int* in_sizes, int n_in,
                              void* d_out, int out_size, void* d_ws, size_t ws_size,
                              hipStream_t stream) {
    const float* in1  = (const float*)d_in[0];
    const float* in2  = (const float*)d_in[1];
    const float* xyz1 = (const float*)d_in[2];
    const float* xyz2 = (const float*)d_in[3];
    const int*   mask = (const int*)d_in[4];
    const float* Wr1  = (const float*)d_in[5];
    const float* Wro  = (const float*)d_in[6];
    const float* Wfc3 = (const float*)d_in[7];
    const float* Wfc2 = (const float*)d_in[8];
    float* out = (float*)d_out;

    float* T       = (float*)d_ws;                   // Z*NN*H*C floats = 1.18 MB
    float* partial = T + Z * NN * H * C;             // Z*NAT*SPLIT*64 = 590 KB

    k1_precompute_T<<<Z * NN, 192, 0, stream>>>(in1, in2, Wro, T);
    k2_pairs<<<Z * NAT * SPLIT, 128, 0, stream>>>(xyz1, xyz2, Wr1, T, partial);
    k3_head<<<Z, 256, 0, stream>>>(partial, mask, Wfc3, Wfc2, out);
}

// Round 5
// 100.201 us; speedup vs baseline: 1.1542x; 1.1542x over previous
//
#include <hip/hip_runtime.h>
#include <math.h>

#define Z     4
#define N1    192
#define NN    384          // n1 + n2
#define C     16
#define NB    10
#define H     12
#define ATILE 4
#define NAT   (NN / ATILE) // 96
#define SPLIT 6            // b-splits: 6 * 64 lanes = 384 b's

// ---------------------------------------------------------------------------
__device__ __forceinline__ float3 load_xyz(const float* __restrict__ xyz1,
                                           const float* __restrict__ xyz2,
                                           int z, int node) {
    const float* p = (node < N1) ? (xyz1 + (z * N1 + node) * 3)
                                 : (xyz2 + (z * N1 + (node - N1)) * 3);
    return make_float3(p[0], p[1], p[2]);
}

// ---------------------------------------------------------------------------
// Kernel 1: T[z][h][i][b] = (Y0/sqrt(H)) * sum_j W_rad_out[h, i*16+j] * x[z,b,j]
// (b innermost so k2's lane-per-b reads are coalesced).
// grid = Z*NN blocks, 192 threads (one per (h,i)).
// ---------------------------------------------------------------------------
__global__ void k1_precompute_T(const float* __restrict__ in1,
                                const float* __restrict__ in2,
                                const float* __restrict__ Wro,
                                float* __restrict__ T) {
    const int bid = blockIdx.x;          // z*NN + b
    const int z = bid / NN, b = bid % NN;
    const int t = threadIdx.x;           // 0..191  -> h = t>>4, i = t&15

    __shared__ float xl[C];
    if (t < C) {
        const float* xp = (b < N1) ? (in1 + (z * N1 + b) * C)
                                   : (in2 + (z * N1 + (b - N1)) * C);
        xl[t] = xp[t];
    }
    __syncthreads();

    const int h = t >> 4, i = t & 15;
    const float* w = Wro + h * (C * C) + i * C;
    float acc = 0.0f;
    #pragma unroll
    for (int j = 0; j < C; ++j) acc += w[j] * xl[j];

    // Y0 = 1/(2*sqrt(pi)) ; 1/sqrt(12)
    const float scale = 0.28209479177387814f * 0.2886751345948129f;
    T[((z * H + h) * C + i) * NN + b] = acc * scale;   // transposed store
}

// ---------------------------------------------------------------------------
// Kernel 2: block = (z, tile of 4 a's, 1-of-6 b-split). 128 threads = 2 waves.
// Both waves cover the SAME 64 b's (b = sp*64 + lane); wave wv owns the
// i-halfrange [wv*8, wv*8+8). T reads are coalesced scalar loads (b innermost).
// ---------------------------------------------------------------------------
__global__ __launch_bounds__(128, 4) void k2_pairs(const float* __restrict__ xyz1,
                                                   const float* __restrict__ xyz2,
                                                   const float* __restrict__ Wr1,
                                                   const float* __restrict__ T,
                                                   float* __restrict__ partial) {
    const int bid = blockIdx.x;          // (z*NAT + at)*SPLIT + sp
    const int sp  = bid % SPLIT;
    const int za  = bid / SPLIT;
    const int z   = za / NAT, at = za % NAT;
    const int a0  = at * ATILE;
    const int tid = threadIdx.x;
    const int lane = tid & 63, wv = tid >> 6;
    const int b = sp * 64 + lane;        // this lane's b

    __shared__ float W1s[NB * H];        // [k][h], k*48B rows -> 16B aligned
    __shared__ float red[2][32];
    if (tid < NB * H)
        W1s[tid] = Wr1[tid] * (0.31622776601683794f * 0.7027283689263438f);
    __syncthreads();

    const float3 pb = load_xyz(xyz1, xyz2, z, b);
    const float invSigma = 1.125f;       // 1/(0.8*10/9)

    // ---- distances to the 4 (block-uniform) a's -------------------------
    float dd[ATILE];
    #pragma unroll
    for (int aa = 0; aa < ATILE; ++aa) {
        const float3 pa = load_xyz(xyz1, xyz2, z, a0 + aa);
        const float dx = pa.x - pb.x, dy = pa.y - pb.y, dz = pa.z - pb.z;
        dd[aa] = sqrtf(dx * dx + dy * dy + dz * dz + 1e-12f);
    }

    // ---- phase 1: acc[aa][h] = sum_k exp(..) * W1s[k][h] ----------------
    // k-outer so each W float4 is read once and shared across all 4 a's.
    float acc[ATILE][H];
    #pragma unroll
    for (int aa = 0; aa < ATILE; ++aa)
        #pragma unroll
        for (int h = 0; h < H; ++h) acc[aa][h] = 0.0f;

    #pragma unroll
    for (int k = 0; k < NB; ++k) {
        const float4 w0 = *(const float4*)&W1s[k * H + 0];
        const float4 w1 = *(const float4*)&W1s[k * H + 4];
        const float4 w2 = *(const float4*)&W1s[k * H + 8];
        const float ck = (float)k * (10.0f / 9.0f);
        #pragma unroll
        for (int aa = 0; aa < ATILE; ++aa) {
            const float u = (dd[aa] - ck) * invSigma;
            const float e = __expf(-u * u);
            acc[aa][0]  += e * w0.x;  acc[aa][1]  += e * w0.y;
            acc[aa][2]  += e * w0.z;  acc[aa][3]  += e * w0.w;
            acc[aa][4]  += e * w1.x;  acc[aa][5]  += e * w1.y;
            acc[aa][6]  += e * w1.z;  acc[aa][7]  += e * w1.w;
            acc[aa][8]  += e * w2.x;  acc[aa][9]  += e * w2.y;
            acc[aa][10] += e * w2.z;  acc[aa][11] += e * w2.w;
        }
    }
    float hm[ATILE][H];
    #pragma unroll
    for (int aa = 0; aa < ATILE; ++aa)
        #pragma unroll
        for (int h = 0; h < H; ++h)
            hm[aa][h] = acc[aa][h] / (1.0f + __expf(-acc[aa][h]));   // silu

    // ---- phase 2: v[aa*8+io] += hm[aa][h] * T[z][h][wv*8+io][b] ---------
    float v[ATILE * 8];
    #pragma unroll
    for (int p = 0; p < ATILE * 8; ++p) v[p] = 0.0f;

    const float* tb = T + ((z * H) * C + wv * 8) * NN + b;   // coalesced base
    #pragma unroll
    for (int h = 0; h < H; ++h) {
        #pragma unroll
        for (int io = 0; io < 8; ++io) {
            const float tval = tb[(h * C + io) * NN];
            #pragma unroll
            for (int aa = 0; aa < ATILE; ++aa)
                v[aa * 8 + io] += hm[aa][h] * tval;
        }
    }

    // ---- fold-reduce 32 values across 64 lanes --------------------------
    // 5 value-halving xor steps (bits 0..4) then a plain xor-32 add.
    #pragma unroll
    for (int k = 0; k < 5; ++k) {
        const int m = 16 >> k;
        const int bsel = (lane >> k) & 1;
        #pragma unroll
        for (int j = 0; j < m; ++j) {
            const float lo = v[j], hi = v[m + j];
            const float sendv = bsel ? lo : hi;
            const float recv = __shfl_xor(sendv, 1 << k, 64);
            v[j] = (bsel ? hi : lo) + recv;
        }
    }
    {
        const float recv = __shfl_xor(v[0], 32, 64);
        v[0] += recv;
    }
    const int l = lane & 31;
    const int pos = ((l & 1) << 4) | ((l & 2) << 2) | (l & 4) |
                    ((l & 8) >> 2) | ((l & 16) >> 4);      // bitrev5
    if (lane < 32) red[wv][pos] = v[0];
    __syncthreads();

    if (tid < 64) {                       // partial[bid][a_off*16 + i]
        const int a_off = tid >> 4, i = tid & 15;
        const float val = (i < 8) ? red[0][a_off * 8 + i]
                                  : red[1][a_off * 8 + (i - 8)];
        partial[bid * 64 + tid] = val;
    }
}

// ---------------------------------------------------------------------------
// Kernel 3: per z: sum splits, abs, mask, sum over a -> s[16];
// then normalize (ddof=1) + fc3 + leaky_relu + fc2 + sigmoid.
// grid = Z blocks, 256 threads.
// ---------------------------------------------------------------------------
__global__ __launch_bounds__(256) void k3_head(const float* __restrict__ partial,
                                               const int* __restrict__ mask,
                                               const float* __restrict__ Wfc3,
                                               const float* __restrict__ Wfc2,
                                               float* __restrict__ out) {
    const int z = blockIdx.x;
    const int t = threadIdx.x;           // 256 = 16 chunks x 16 i
    const int i = t & 15, ch = t >> 4;

    __shared__ float red[16][17];
    __shared__ float sv[C];

    float acc = 0.0f;
    #pragma unroll
    for (int r = 0; r < 24; ++r) {       // 16 chunks * 24 = 384 a's
        const int a  = ch * 24 + r;
        const int at = a >> 2, t2 = a & 3;
        const int base = ((z * NAT + at) * SPLIT) * 64 + t2 * 16 + i;
        float val = 0.0f;
        #pragma unroll
        for (int s = 0; s < SPLIT; ++s) val += partial[base + s * 64];
        val = fabsf(val);
        if (mask[z * NN + a] != 0) acc += val;
    }
    red[ch][i] = acc;
    __syncthreads();
    if (t < C) {
        float s = 0.0f;
        #pragma unroll
        for (int c2 = 0; c2 < 16; ++c2) s += red[c2][t];
        sv[t] = s;
    }
    __syncthreads();

    if (t == 0) {
        float v[C];
        float mean = 0.0f;
        #pragma unroll
        for (int q = 0; q < C; ++q) { v[q] = sv[q]; mean += v[q]; }
        mean *= (1.0f / C);
        float var = 0.0f;
        #pragma unroll
        for (int q = 0; q < C; ++q) { const float d = v[q] - mean; var += d * d; }
        const float sd = sqrtf(var / (float)(C - 1)) + 1e-6f;
        #pragma unroll
        for (int q = 0; q < C; ++q) v[q] = (v[q] - mean) / sd;

        float o = 0.0f;
        #pragma unroll
        for (int k = 0; k < C; ++k) {
            float h3 = 0.0f;
            #pragma unroll
            for (int q = 0; q < C; ++q) h3 += v[q] * Wfc3[q * C + k];
            h3 *= 0.25f;                               // / sqrt(16)
            h3 = (h3 > 0.0f) ? h3 : 0.01f * h3;        // leaky_relu
            o += h3 * Wfc2[k];
        }
        o *= 0.25f;
        out[z] = 1.0f / (1.0f + __expf(-o));
    }
}

// ---------------------------------------------------------------------------
extern "C" void kernel_launch(void* const* d_in, const int* in_sizes, int n_in,
                              void* d_out, int out_size, void* d_ws, size_t ws_size,
                              hipStream_t stream) {
    const float* in1  = (const float*)d_in[0];
    const float* in2  = (const float*)d_in[1];
    const float* xyz1 = (const float*)d_in[2];
    const float* xyz2 = (const float*)d_in[3];
    const int*   mask = (const int*)d_in[4];
    const float* Wr1  = (const float*)d_in[5];
    const float* Wro  = (const float*)d_in[6];
    const float* Wfc3 = (const float*)d_in[7];
    const float* Wfc2 = (const float*)d_in[8];
    float* out = (float*)d_out;

    float* T       = (float*)d_ws;                   // Z*H*C*NN floats = 1.18 MB
    float* partial = T + Z * NN * H * C;             // Z*NAT*SPLIT*64 = 590 KB

    k1_precompute_T<<<Z * NN, 192, 0, stream>>>(in1, in2, Wro, T);
    k2_pairs<<<Z * NAT * SPLIT, 128, 0, stream>>>(xyz1, xyz2, Wr1, T, partial);
    k3_head<<<Z, 256, 0, stream>>>(partial, mask, Wfc3, Wfc2, out);
}

// Round 8
// 95.450 us; speedup vs baseline: 1.2117x; 1.0498x over previous
//
#include <hip/hip_runtime.h>
#include <math.h>

#define Z     4
#define N1    192
#define NN    384          // n1 + n2
#define C     16
#define NB    10
#define H     12
#define ATILE 4
#define NAT   (NN / ATILE) // 96
#define SPLIT 6            // b-splits: 6 * 64 lanes = 384 b's

// fast native ops (hardware VALU, ~1 ulp)
__device__ __forceinline__ float fexp2(float x) {
    float r; asm volatile("v_exp_f32 %0, %1" : "=v"(r) : "v"(x)); return r;
}
__device__ __forceinline__ float frcp(float x) {
    float r; asm volatile("v_rcp_f32 %0, %1" : "=v"(r) : "v"(x)); return r;
}

// ---------------------------------------------------------------------------
__device__ __forceinline__ float3 load_xyz(const float* __restrict__ xyz1,
                                           const float* __restrict__ xyz2,
                                           int z, int node) {
    const float* p = (node < N1) ? (xyz1 + (z * N1 + node) * 3)
                                 : (xyz2 + (z * N1 + (node - N1)) * 3);
    return make_float3(p[0], p[1], p[2]);
}

// ---------------------------------------------------------------------------
// Kernel 1: T[z][h][i][b] = (Y0/sqrt(H)) * sum_j W_rad_out[h, i*16+j] * x[z,b,j]
// (b innermost so k2's lane-per-b reads are coalesced). Also zeros y_acc.
// grid = Z*NN blocks, 192 threads (one per (h,i)).
// ---------------------------------------------------------------------------
__global__ void k1_precompute_T(const float* __restrict__ in1,
                                const float* __restrict__ in2,
                                const float* __restrict__ Wro,
                                float* __restrict__ T,
                                float* __restrict__ y_acc) {
    const int bid = blockIdx.x;          // z*NN + b
    const int z = bid / NN, b = bid % NN;
    const int t = threadIdx.x;           // 0..191  -> h = t>>4, i = t&15

    __shared__ float xl[C];
    if (t < C) {
        const float* xp = (b < N1) ? (in1 + (z * N1 + b) * C)
                                   : (in2 + (z * N1 + (b - N1)) * C);
        xl[t] = xp[t];
    }
    if (bid < 128) y_acc[bid * 192 + t] = 0.0f;    // 128*192 = Z*NN*C exactly
    __syncthreads();

    const int h = t >> 4, i = t & 15;
    const float* w = Wro + h * (C * C) + i * C;
    float acc = 0.0f;
    #pragma unroll
    for (int j = 0; j < C; ++j) acc += w[j] * xl[j];

    // Y0 = 1/(2*sqrt(pi)) ; 1/sqrt(12)
    const float scale = 0.28209479177387814f * 0.2886751345948129f;
    T[((z * H + h) * C + i) * NN + b] = acc * scale;   // transposed store
}

// ---------------------------------------------------------------------------
// Kernel 2: block = (z, tile of 4 a's, 1-of-6 b-split). ONE wave (64 threads),
// lane = b. Full i-range per lane: 64 accumulators.
// Fold-reduce 64 values across lanes, then one wave-atomicAdd into y_acc.
// ---------------------------------------------------------------------------
__global__ __launch_bounds__(64) void k2_pairs(const float* __restrict__ xyz1,
                                               const float* __restrict__ xyz2,
                                               const float* __restrict__ Wr1,
                                               const float* __restrict__ T,
                                               float* __restrict__ y_acc) {
    const int bid = blockIdx.x;          // (z*NAT + at)*SPLIT + sp
    const int sp  = bid % SPLIT;
    const int za  = bid / SPLIT;
    const int z   = za / NAT, at = za % NAT;
    const int a0  = at * ATILE;
    const int lane = threadIdx.x;
    const int b = sp * 64 + lane;        // this lane's b

    __shared__ float W1s[NB * H];        // [k][h] * invGN / sqrt(NB)
    // NB*H = 120 > 64 lanes: MUST loop (R6/R7 bug: single-pass load left
    // W1s[64..119] uninitialized -> garbage for basis centers k>=6).
    for (int idx = lane; idx < NB * H; idx += 64)
        W1s[idx] = Wr1[idx] * (0.31622776601683794f * 0.7027283689263438f);
    __syncthreads();

    const float3 pb = load_xyz(xyz1, xyz2, z, b);

    // ---- distances ------------------------------------------------------
    float dd[ATILE];
    #pragma unroll
    for (int aa = 0; aa < ATILE; ++aa) {
        const float3 pa = load_xyz(xyz1, xyz2, z, a0 + aa);
        const float dx = pa.x - pb.x, dy = pa.y - pb.y, dz = pa.z - pb.z;
        dd[aa] = sqrtf(dx * dx + dy * dy + dz * dz + 1e-12f);
    }

    // ---- phase 1: hm[aa][h] = silu( sum_k gauss_k(d_aa) * W1s[k][h] ) ----
    // gauss = exp(-((d-ck)/sigma)^2) = exp2(-invSig^2*log2e * (d-ck)^2);
    // invSig^2*log2e = (81/64)*1.4426950408889634 = 1.8259109111250943.
    float hm[ATILE][H];
    #pragma unroll
    for (int aa = 0; aa < ATILE; ++aa)
        #pragma unroll
        for (int h = 0; h < H; ++h) hm[aa][h] = 0.0f;

    #pragma unroll
    for (int k = 0; k < NB; ++k) {
        const float4 w0 = *(const float4*)&W1s[k * H + 0];
        const float4 w1 = *(const float4*)&W1s[k * H + 4];
        const float4 w2 = *(const float4*)&W1s[k * H + 8];
        const float ck = (float)k * (10.0f / 9.0f);
        #pragma unroll
        for (int aa = 0; aa < ATILE; ++aa) {
            const float t = dd[aa] - ck;
            const float e = fexp2(t * t * -1.8259109111250943f);
            hm[aa][0]  += e * w0.x;  hm[aa][1]  += e * w0.y;
            hm[aa][2]  += e * w0.z;  hm[aa][3]  += e * w0.w;
            hm[aa][4]  += e * w1.x;  hm[aa][5]  += e * w1.y;
            hm[aa][6]  += e * w1.z;  hm[aa][7]  += e * w1.w;
            hm[aa][8]  += e * w2.x;  hm[aa][9]  += e * w2.y;
            hm[aa][10] += e * w2.z;  hm[aa][11] += e * w2.w;
        }
    }
    #pragma unroll
    for (int aa = 0; aa < ATILE; ++aa)
        #pragma unroll
        for (int h = 0; h < H; ++h) {
            const float x = hm[aa][h];
            const float sig = frcp(1.0f + fexp2(x * -1.4426950408889634f));
            hm[aa][h] = x * sig;                       // silu
        }

    // ---- phase 2: v[aa*16+i] += hm[aa][h] * T[z][h][i][b] ----------------
    float v[ATILE * C];
    #pragma unroll
    for (int p = 0; p < ATILE * C; ++p) v[p] = 0.0f;

    const float* tb = T + (z * H * C) * NN + b;        // coalesced base (lane=b)
    #pragma unroll
    for (int h = 0; h < H; ++h) {
        #pragma unroll
        for (int i = 0; i < C; ++i) {
            const float tval = tb[(h * C + i) * NN];
            #pragma unroll
            for (int aa = 0; aa < ATILE; ++aa)
                v[aa * C + i] += hm[aa][h] * tval;
        }
    }

    // ---- fold-reduce 64 values across 64 lanes ---------------------------
    // 6 value-halving xor steps; lane l ends with sum for position bitrev6(l).
    #pragma unroll
    for (int k = 0; k < 6; ++k) {
        const int m = 32 >> k;
        const int bsel = (lane >> k) & 1;
        #pragma unroll
        for (int j = 0; j < m; ++j) {
            const float lo = v[j], hi = v[m + j];
            const float sendv = bsel ? lo : hi;
            const float recv = __shfl_xor(sendv, 1 << k, 64);
            v[j] = (bsel ? hi : lo) + recv;
        }
    }
    const int l = lane;
    const int pos = ((l & 1) << 5) | ((l & 2) << 3) | ((l & 4) << 1) |
                    ((l & 8) >> 1) | ((l & 16) >> 3) | ((l & 32) >> 5);  // bitrev6
    // pos = a_off*16 + i ;  (a0+a_off)*C + i == a0*C + pos
    atomicAdd(&y_acc[(z * NN + a0) * C + pos], v[0]);
}

// ---------------------------------------------------------------------------
// Kernel 3: per z: abs, mask, sum over a -> s[16]; then normalize (ddof=1,
// two-pass) + fc3 + leaky_relu + fc2 + sigmoid. grid = Z blocks, 256 threads.
// ---------------------------------------------------------------------------
__global__ __launch_bounds__(256) void k3_head(const float* __restrict__ y_acc,
                                               const int* __restrict__ mask,
                                               const float* __restrict__ Wfc3,
                                               const float* __restrict__ Wfc2,
                                               float* __restrict__ out) {
    const int z = blockIdx.x;
    const int t = threadIdx.x;           // 256 = 16 chunks x 16 i
    const int i = t & 15, ch = t >> 4;

    __shared__ float red[16][17];

    float acc = 0.0f;
    #pragma unroll
    for (int r = 0; r < 24; ++r) {       // 16 chunks * 24 = 384 a's
        const int a = ch * 24 + r;
        const float val = y_acc[(z * NN + a) * C + i];
        if (mask[z * NN + a] != 0) acc += fabsf(val);
    }
    red[ch][i] = acc;
    __syncthreads();

    if (t < C) {                          // lanes 0..15 of wave 0
        float x = 0.0f;
        #pragma unroll
        for (int c2 = 0; c2 < 16; ++c2) x += red[c2][t];

        // mean over the 16 lanes
        float m = x;
        #pragma unroll
        for (int msk = 1; msk < 16; msk <<= 1) m += __shfl_xor(m, msk, 64);
        m *= (1.0f / 16.0f);
        // two-pass variance (ddof=1)
        const float dv = x - m;
        float vv = dv * dv;
        #pragma unroll
        for (int msk = 1; msk < 16; msk <<= 1) vv += __shfl_xor(vv, msk, 64);
        const float sd = sqrtf(vv / 15.0f) + 1e-6f;
        const float xn = dv / sd;         // normalized s[t]

        // h3[k=t] = leaky( 0.25 * sum_q xn_q * Wfc3[q][t] )
        float h3 = 0.0f;
        #pragma unroll
        for (int q = 0; q < 16; ++q)
            h3 += __shfl(xn, q, 64) * Wfc3[q * C + t];
        h3 *= 0.25f;
        h3 = (h3 > 0.0f) ? h3 : 0.01f * h3;

        float o = h3 * Wfc2[t];
        #pragma unroll
        for (int msk = 1; msk < 16; msk <<= 1) o += __shfl_xor(o, msk, 64);
        if (t == 0) out[z] = 1.0f / (1.0f + __expf(-0.25f * o));
    }
}

// ---------------------------------------------------------------------------
extern "C" void kernel_launch(void* const* d_in, const int* in_sizes, int n_in,
                              void* d_out, int out_size, void* d_ws, size_t ws_size,
                              hipStream_t stream) {
    const float* in1  = (const float*)d_in[0];
    const float* in2  = (const float*)d_in[1];
    const float* xyz1 = (const float*)d_in[2];
    const float* xyz2 = (const float*)d_in[3];
    const int*   mask = (const int*)d_in[4];
    const float* Wr1  = (const float*)d_in[5];
    const float* Wro  = (const float*)d_in[6];
    const float* Wfc3 = (const float*)d_in[7];
    const float* Wfc2 = (const float*)d_in[8];
    float* out = (float*)d_out;

    float* T     = (float*)d_ws;                     // Z*H*C*NN floats = 1.18 MB
    float* y_acc = T + Z * NN * H * C;               // Z*NN*C floats = 96 KB

    k1_precompute_T<<<Z * NN, 192, 0, stream>>>(in1, in2, Wro, T, y_acc);
    k2_pairs<<<Z * NAT * SPLIT, 64, 0, stream>>>(xyz1, xyz2, Wr1, T, y_acc);
    k3_head<<<Z, 256, 0, stream>>>(y_acc, mask, Wfc3, Wfc2, out);
}